// Round 10
// baseline (373.605 us; speedup 1.0000x reference)
//
#include <hip/hip_runtime.h>
#include <hip/hip_bf16.h>
#include <math.h>
#include <stdint.h>

// R14: node split into two lean kernels (edge/init = R13 verbatim).
//      R13 post-mortem: edge hit its line-event floor (137us ~= predicted 139),
//      but total only -21.5 => node still ~110-120us (hidden under the 136us
//      top-5 cutoff). R12 counters showed the cause: compiler allocates <=128
//      VGPR while GEMM context + divergent circuit + staging state overlap ->
//      scratch spill (50MB writes) + private-segment wave throttling (0.3% occ).
//      Fix: no kernel holds GEMM state and the circuit at once.
//        node_q: h,agg -> qGEMMs -> circuit -> qsc[node][4] f32 (ws scratch)
//        node_p: h,agg,qsc -> pGEMMs -> out          (no circuit)
//      Cost: +1 launch, ~20MB re-read (~3us), 0.8MB qout round-trip.

#define N_NODES 50000
#define N_EDGES 800000
#define DIM 64
#define HID 64
#define T_EDGE (N_EDGES / 16)   // 50000 tiles of 16 edges
#define T_NODE (N_NODES / 16)   // 3125 tiles of 16 nodes (exact)
#define EDGE_GRID 512           // 2 blocks/CU (LDS 64000B) * 256 CU
#define EWAVES 16               // 1024-thread edge blocks
#define NODE_GRID 392           // 392*8 waves = 3136 >= 3125 tiles, 1 tile/wave

typedef __bf16 bf16_t;
typedef __bf16 bf16x8 __attribute__((ext_vector_type(8)));
typedef float f32x4 __attribute__((ext_vector_type(4)));

__device__ __forceinline__ float silu_f(float x) {
    return x * __builtin_amdgcn_rcpf(1.f + __expf(-x));
}

__device__ __forceinline__ f32x4 mfma16(bf16x8 a, bf16x8 b, f32x4 c) {
    return __builtin_amdgcn_mfma_f32_16x16x32_bf16(a, b, c, 0, 0, 0);
}

// load 8 consecutive fp32 (32B-aligned) and convert to a bf16 fragment
__device__ __forceinline__ bf16x8 cvt8(const float* __restrict__ p) {
    f32x4 u0 = *(const f32x4*)p;
    f32x4 u1 = *(const f32x4*)(p + 4);
    bf16x8 r;
    r[0] = (bf16_t)u0[0]; r[1] = (bf16_t)u0[1]; r[2] = (bf16_t)u0[2]; r[3] = (bf16_t)u0[3];
    r[4] = (bf16_t)u1[0]; r[5] = (bf16_t)u1[1]; r[6] = (bf16_t)u1[2]; r[7] = (bf16_t)u1[3];
    return r;
}

// ---------------------------------------------------------------------------
// Init: zero bf16 agg + convert h fp32 -> bf16 (both N_NODES*64 elements)
// ---------------------------------------------------------------------------
__global__ __launch_bounds__(256) void init_kernel(const float* __restrict__ h,
                                                   bf16_t* __restrict__ hb,
                                                   bf16_t* __restrict__ aggz, int n8)
{
    int i = blockIdx.x * 256 + threadIdx.x;
    if (i < n8) {
        *(bf16x8*)(hb + (size_t)i * 8) = cvt8(h + (size_t)i * 8);
        bf16x8 zz;
        #pragma unroll
        for (int j = 0; j < 8; ++j) zz[j] = (bf16_t)0.f;
        *(bf16x8*)(aggz + (size_t)i * 8) = zz;
    }
}

// ---------------------------------------------------------------------------
// Edge kernel: R13 verbatim. Persistent, 16 waves x one 16-edge tile per
// iteration, software-pipelined 1 tile deep. GEMM1 -> silu -> bf16 sHid
// (wave-private, no barrier) -> GEMM2 -> scalar mij stores + full-64B-line
// pk-bf16 atomic instructions (8 instrs, 32 line-events/tile).
// ---------------------------------------------------------------------------
__global__ __launch_bounds__(1024) void edge_kernel(
    const bf16_t* __restrict__ hb,
    const int* __restrict__ ei,
    const float* __restrict__ eW1, const float* __restrict__ eb1,
    const float* __restrict__ eW2, const float* __restrict__ eb2,
    float* __restrict__ mij_out,
    bf16_t* __restrict__ agg)
{
    __shared__ __align__(16) bf16_t sB1[64][136];    // eW1^T [n][k], k<128 (17408B)
    __shared__ __align__(16) bf16_t sB2[64][72];     // eW2^T [n][k], k<64   (9216B)
    __shared__ __align__(16) bf16_t sHid[EWAVES][16][72];  // 36864B
    __shared__ float sb1[64], sb2[64];               // 512B  -> total 64000B

    const int tid = threadIdx.x;
    for (int idx = tid; idx < 128 * 64; idx += 1024) {
        int k = idx >> 6, n = idx & 63;
        sB1[n][k] = (bf16_t)eW1[idx];
    }
    for (int idx = tid; idx < 64 * 64; idx += 1024) {
        int k = idx >> 6, n = idx & 63;
        sB2[n][k] = (bf16_t)eW2[idx];
    }
    if (tid < 64) { sb1[tid] = eb1[tid]; sb2[tid] = eb2[tid]; }
    __syncthreads();

    const int l = tid & 63, wave = tid >> 6;
    const int m = l & 15, quad = l >> 4;
    const int eisel = m + ((quad & 1) ? N_EDGES : 0);
    const f32x4 z = {0.f, 0.f, 0.f, 0.f};

    int t = blockIdx.x * EWAVES + wave;
    if (t >= T_EDGE) return;

    // ---- prologue: ei + gathers for first tile
    int ev = ei[t * 16 + eisel];
    int nrow = __shfl(ev, m);
    int ncol = __shfl(ev, 16 + m);
    bf16x8 a_cur[4];
    {
        const bf16_t* ra = hb + (size_t)nrow * DIM;
        const bf16_t* rb = hb + (size_t)ncol * DIM;
        #pragma unroll
        for (int ks = 0; ks < 4; ++ks) {
            const int k0 = ks * 32 + quad * 8;
            a_cur[ks] = *(const bf16x8*)((k0 < 64) ? (ra + k0) : (rb + (k0 - 64)));
        }
    }

    while (true) {
        const int e0 = t * 16;
        const int tn = t + EDGE_GRID * EWAVES;
        const bool has_next = (tn < T_EDGE);

        // issue next tile's ei load (latency hidden under GEMM1)
        int evn = 0;
        if (has_next) evn = ei[tn * 16 + eisel];

        // GEMM1: [h_row || h_col] @ eW1 (standard layout: D[edge][chan])
        f32x4 acc[4] = {z, z, z, z};
        #pragma unroll
        for (int ks = 0; ks < 4; ++ks) {
            const int k0 = ks * 32 + quad * 8;
            #pragma unroll
            for (int nt = 0; nt < 4; ++nt)
                acc[nt] = mfma16(a_cur[ks], *(const bf16x8*)&sB1[nt * 16 + m][k0], acc[nt]);
        }
        #pragma unroll
        for (int nt = 0; nt < 4; ++nt)
            #pragma unroll
            for (int rr = 0; rr < 4; ++rr) {
                int row = quad * 4 + rr, col = nt * 16 + m;
                sHid[wave][row][col] = (bf16_t)silu_f(acc[nt][rr] + sb1[col]);
            }
        // sHid[wave] is wave-private; DS ops in-order per wave -> no barrier

        // issue next tile's gathers (latency hidden under GEMM2 + epilogue)
        int nrow_n = 0, ncol_n = 0;
        bf16x8 a_nxt[4];
        if (has_next) {
            nrow_n = __shfl(evn, m);
            ncol_n = __shfl(evn, 16 + m);
            const bf16_t* ra = hb + (size_t)nrow_n * DIM;
            const bf16_t* rb = hb + (size_t)ncol_n * DIM;
            #pragma unroll
            for (int ks = 0; ks < 4; ++ks) {
                const int k0 = ks * 32 + quad * 8;
                a_nxt[ks] = *(const bf16x8*)((k0 < 64) ? (ra + k0) : (rb + (k0 - 64)));
            }
        }

        // GEMM2: hidden @ eW2 (standard layout)
        f32x4 acc2[4] = {z, z, z, z};
        #pragma unroll
        for (int ks = 0; ks < 2; ++ks) {
            const int k0 = ks * 32 + quad * 8;
            bf16x8 a = *(const bf16x8*)&sHid[wave][m][k0];
            #pragma unroll
            for (int nt = 0; nt < 4; ++nt)
                acc2[nt] = mfma16(a, *(const bf16x8*)&sB2[nt * 16 + m][k0], acc2[nt]);
        }

        int dstrow[4];
        #pragma unroll
        for (int rr = 0; rr < 4; ++rr) dstrow[rr] = __shfl(nrow, quad * 4 + rr);

        // epilogue: scalar mij stores + full-64B-line atomic instructions
        #pragma unroll
        for (int rr = 0; rr < 4; ++rr) {
            uint32_t pku[4];
            #pragma unroll
            for (int nt = 0; nt < 4; ++nt) {
                const int col = nt * 16 + m;
                float v = silu_f(acc2[nt][rr] + sb2[col]);
                __builtin_nontemporal_store(
                    v, &mij_out[(size_t)(e0 + quad * 4 + rr) * HID + col]);
                float vh = __shfl_xor(v, 1);   // partner column's value
                union { bf16_t h2[2]; uint32_t u; } pk;
                pk.h2[0] = (bf16_t)v; pk.h2[1] = (bf16_t)vh;
                pku[nt] = pk.u;                // valid pair order in even lanes
            }
            bf16_t* rowp = agg + (size_t)dstrow[rr] * HID;
            const int src = (l & 48) | ((2 * m) & 15);   // even lane, same quad
            #pragma unroll
            for (int B = 0; B < 2; ++B) {
                uint32_t ua = (uint32_t)__shfl((int)pku[2 * B], src);
                uint32_t ub = (uint32_t)__shfl((int)pku[2 * B + 1], src);
                uint32_t u = (m >= 8) ? ub : ua;
                const int c = 32 * B + 2 * m;
                asm volatile("global_atomic_pk_add_bf16 %0, %1, off"
                             :: "v"((uint64_t)(uintptr_t)(rowp + c)), "v"(u)
                             : "memory");
            }
        }

        if (!has_next) break;
        t = tn;
        nrow = nrow_n; ncol = ncol_n;
        #pragma unroll
        for (int ks = 0; ks < 4; ++ks) a_cur[ks] = a_nxt[ks];
    }
}

// ---------------------------------------------------------------------------
// Node Q kernel: one 16-node tile per wave.
//   t = silu([h,agg*0.01] @ qW1 + qb1); qin = t @ qW2 + qb2 (MFMA);
//   3-qubit circuit (lane<16); qout -> qsc[node][4] fp32.
//   GEMM accumulators are dead before the circuit -> no spill.
// ---------------------------------------------------------------------------
__global__ __launch_bounds__(512) void node_q_kernel(
    const float* __restrict__ h, const bf16_t* __restrict__ aggb,
    const float* __restrict__ qW1, const float* __restrict__ qb1,
    const float* __restrict__ qW2, const float* __restrict__ qb2,
    const float* __restrict__ al_p, const float* __restrict__ be_p,
    const float* __restrict__ ga_p, const float* __restrict__ de_p,
    const float* __restrict__ lam_p,
    float* __restrict__ qsc)
{
    __shared__ __align__(16) bf16_t sQ1[64][136];   // qW1^T, rows 64..127 *0.01
    __shared__ __align__(16) bf16_t sQ2b[16][72];   // qW2^T padded to 16 cols
    __shared__ __align__(16) bf16_t sHid[8][16][72];
    __shared__ float sQio[8][16][4];
    __shared__ float sqb1[64], sqb2[4];

    const int tid = threadIdx.x;
    for (int idx = tid; idx < 128 * 64; idx += 512) {
        int k = idx >> 6, n = idx & 63;
        float w = qW1[idx];
        sQ1[n][k] = (bf16_t)(k < 64 ? w : w * 0.01f);
    }
    for (int idx = tid; idx < 16 * 72; idx += 512) {
        int c = idx / 72, k = idx - c * 72;
        sQ2b[c][k] = (bf16_t)((c < 3 && k < 64) ? qW2[k * 3 + c] : 0.f);
    }
    if (tid < 64) sqb1[tid] = qb1[tid];
    if (tid < 3) sqb2[tid] = qb2[tid];
    __syncthreads();

    const int lane = tid & 63, wave = tid >> 6;
    const int m = lane & 15, quad = lane >> 4;
    const int t = blockIdx.x * 8 + wave;
    if (t >= T_NODE) return;
    const int n0 = t * 16;
    const float* hrow = h + (size_t)(n0 + m) * DIM;
    const bf16_t* grow = aggb + (size_t)(n0 + m) * HID;
    const f32x4 z = {0.f, 0.f, 0.f, 0.f};

    // ---- t = silu(a @ qW1 + qb1)
    {
        f32x4 acc[4] = {z, z, z, z};
        #pragma unroll
        for (int ks = 0; ks < 4; ++ks) {
            const int k0 = ks * 32 + quad * 8;
            bf16x8 a = (k0 < 64) ? cvt8(hrow + k0)
                                 : *(const bf16x8*)(grow + (k0 - 64));
            #pragma unroll
            for (int nt = 0; nt < 4; ++nt)
                acc[nt] = mfma16(a, *(const bf16x8*)&sQ1[nt * 16 + m][k0], acc[nt]);
        }
        #pragma unroll
        for (int nt = 0; nt < 4; ++nt)
            #pragma unroll
            for (int rr = 0; rr < 4; ++rr) {
                int row = quad * 4 + rr, col = nt * 16 + m;
                sHid[wave][row][col] = (bf16_t)silu_f(acc[nt][rr] + sqb1[col]);
            }
    }

    // ---- q_in = t @ qW2 + qb2 (cols 3..15 zero-padded)
    {
        f32x4 aq = z;
        #pragma unroll
        for (int ks = 0; ks < 2; ++ks) {
            const int k0 = ks * 32 + quad * 8;
            bf16x8 a = *(const bf16x8*)&sHid[wave][m][k0];
            bf16x8 b = *(const bf16x8*)&sQ2b[m][k0];
            aq = mfma16(a, b, aq);
        }
        if (m < 3) {
            #pragma unroll
            for (int rr = 0; rr < 4; ++rr)
                sQio[wave][quad * 4 + rr][m] = aq[rr] + sqb2[m];
        }
    }

    // ---- quantum circuit, one lane per node (fast trig: |angles| << 1)
    if (lane < 16) {
        const float al = al_p[0], be = be_p[0];
        const float ga = ga_p[0], de = de_p[0];
        const float phi01 = ga * (lam_p[1] + lam_p[3]) * 0.5f;
        const float phi02 = ga * (lam_p[2] + lam_p[6]) * 0.5f;
        const float phi12 = ga * (lam_p[5] + lam_p[7]) * 0.5f;
        const float cbg = __cosf(0.5f * be), sbg = __sinf(0.5f * be);

        float qin[3];
        qin[0] = sQio[wave][lane][0];
        qin[1] = sQio[wave][lane][1];
        qin[2] = sQio[wave][lane][2];
        float re[8], im[8];
        float cc[3], ssn[3];
        #pragma unroll
        for (int q = 0; q < 3; ++q) {
            float th = 0.5f * qin[q] * al;
            cc[q] = __cosf(th); ssn[q] = __sinf(th);
        }
        #pragma unroll
        for (int i = 0; i < 8; ++i) {
            float v0 = (i & 4) ? ssn[0] : cc[0];
            float v1 = (i & 2) ? ssn[1] : cc[1];
            float v2 = (i & 1) ? ssn[2] : cc[2];
            re[i] = v0 * v1 * v2; im[i] = 0.f;
        }
        #pragma unroll
        for (int i = 0; i < 8; ++i) {
            float z0 = (i & 4) ? -1.f : 1.f;
            float z1 = (i & 2) ? -1.f : 1.f;
            float z2 = (i & 1) ? -1.f : 1.f;
            float th = -0.5f * (phi01 * z0 * z1 + phi02 * z0 * z2 + phi12 * z1 * z2);
            float ct = __cosf(th), st = __sinf(th);
            float r = re[i], iM = im[i];
            re[i] = r * ct - iM * st;
            im[i] = r * st + iM * ct;
        }
        auto rx = [&]() {
            #pragma unroll
            for (int q = 0; q < 3; ++q) {
                int msk = 4 >> q;
                #pragma unroll
                for (int i = 0; i < 8; ++i) {
                    if (i & msk) continue;
                    int j = i | msk;
                    float r0 = re[i], i0 = im[i], r1 = re[j], i1 = im[j];
                    re[i] = cbg * r0 + sbg * i1;
                    im[i] = cbg * i0 - sbg * r1;
                    re[j] = sbg * i0 + cbg * r1;
                    im[j] = -sbg * r0 + cbg * i1;
                }
            }
        };
        auto hgate = [&](int q) {
            const float inv = 0.70710678f;
            int msk = 4 >> q;
            #pragma unroll
            for (int i = 0; i < 8; ++i) {
                if (i & msk) continue;
                int j = i | msk;
                float r0 = re[i], i0 = im[i], r1 = re[j], i1 = im[j];
                re[i] = (r0 + r1) * inv; im[i] = (i0 + i1) * inv;
                re[j] = (r0 - r1) * inv; im[j] = (i0 - i1) * inv;
            }
        };
        auto rzg = [&](int q, float th) {
            int msk = 4 >> q;
            float c = __cosf(0.5f * th), s = __sinf(0.5f * th);
            #pragma unroll
            for (int i = 0; i < 8; ++i) {
                float sg = (i & msk) ? s : -s;
                float r = re[i], iM = im[i];
                re[i] = r * c - iM * sg;
                im[i] = r * sg + iM * c;
            }
        };
        rx();
        #pragma unroll
        for (int q = 0; q < 3; ++q) {
            float x = qin[q];
            rzg(q, de * (1.f - 0.5f * x * x));
            hgate(q);
            rzg(q, de * x * x);
            hgate(q);
        }
        rx();
        float e0v = 0.f, e1v = 0.f, e2v = 0.f;
        #pragma unroll
        for (int i = 0; i < 8; ++i) {
            float p = re[i] * re[i] + im[i] * im[i];
            e0v += (i & 4) ? -p : p;
            e1v += (i & 2) ? -p : p;
            e2v += (i & 1) ? -p : p;
        }
        f32x4 qo = {e0v, e1v, e2v, 0.f};
        *(f32x4*)(qsc + (size_t)(n0 + lane) * 4) = qo;
    }
}

// ---------------------------------------------------------------------------
// Node P kernel: one 16-node tile per wave. No circuit -> no pressure.
//   u = silu([h, agg*0.01, qout] @ pW1 + pb1); out = h + u @ pW2 + pb2
//   (final GEMM swapped operands -> vector h-load / out-store epilogue).
// ---------------------------------------------------------------------------
__global__ __launch_bounds__(512) void node_p_kernel(
    const float* __restrict__ h, const bf16_t* __restrict__ aggb,
    const float* __restrict__ qsc,
    const float* __restrict__ pW1, const float* __restrict__ pb1,
    const float* __restrict__ pW2, const float* __restrict__ pb2,
    float* __restrict__ out)
{
    __shared__ __align__(16) bf16_t sP1[64][136];   // pW1^T k<131 (rows 64..127 *0.01), k>=131 zero
    __shared__ __align__(16) bf16_t sP2[64][72];    // pW2^T
    __shared__ __align__(16) bf16_t sHid[8][16][72];
    __shared__ __align__(16) float spb1[64];
    __shared__ __align__(16) float spb2[64];

    const int tid = threadIdx.x;
    for (int idx = tid; idx < 131 * 64; idx += 512) {
        int k = idx >> 6, n = idx & 63;
        float w = pW1[idx];
        sP1[n][k] = (bf16_t)((k >= 64 && k < 128) ? w * 0.01f : w);
    }
    for (int idx = tid; idx < 5 * 64; idx += 512) {
        int k = 131 + (idx >> 6), n = idx & 63;
        sP1[n][k] = (bf16_t)0.f;
    }
    for (int idx = tid; idx < 64 * 64; idx += 512) {
        int k = idx >> 6, n = idx & 63;
        sP2[n][k] = (bf16_t)pW2[idx];
    }
    if (tid < 64) { spb1[tid] = pb1[tid]; spb2[tid] = pb2[tid]; }
    __syncthreads();

    const int lane = tid & 63, wave = tid >> 6;
    const int m = lane & 15, quad = lane >> 4;
    const int t = blockIdx.x * 8 + wave;
    if (t >= T_NODE) return;
    const int n0 = t * 16;
    const float* hrow = h + (size_t)(n0 + m) * DIM;
    const bf16_t* grow = aggb + (size_t)(n0 + m) * HID;
    const f32x4 z = {0.f, 0.f, 0.f, 0.f};

    // ---- u = silu([a, q_out] @ pW1 + pb1)
    f32x4 acc2[4] = {z, z, z, z};
    #pragma unroll
    for (int ks = 0; ks < 4; ++ks) {
        const int k0 = ks * 32 + quad * 8;
        bf16x8 a = (k0 < 64) ? cvt8(hrow + k0)
                             : *(const bf16x8*)(grow + (k0 - 64));
        #pragma unroll
        for (int nt = 0; nt < 4; ++nt)
            acc2[nt] = mfma16(a, *(const bf16x8*)&sP1[nt * 16 + m][k0], acc2[nt]);
    }
    {   // K tail 128..135: qout in a[0..2] of quad 0; rest zero
        bf16x8 a, bz;
        #pragma unroll
        for (int j = 0; j < 8; ++j) { a[j] = (bf16_t)0.f; bz[j] = (bf16_t)0.f; }
        if (quad == 0) {
            f32x4 qo = *(const f32x4*)(qsc + (size_t)(n0 + m) * 4);
            a[0] = (bf16_t)qo[0];
            a[1] = (bf16_t)qo[1];
            a[2] = (bf16_t)qo[2];
        }
        #pragma unroll
        for (int nt = 0; nt < 4; ++nt) {
            bf16x8 b = bz;
            if (quad == 0) b = *(const bf16x8*)&sP1[nt * 16 + m][128];
            acc2[nt] = mfma16(a, b, acc2[nt]);
        }
    }
    #pragma unroll
    for (int nt = 0; nt < 4; ++nt)
        #pragma unroll
        for (int rr = 0; rr < 4; ++rr) {
            int row = quad * 4 + rr, col = nt * 16 + m;
            sHid[wave][row][col] = (bf16_t)silu_f(acc2[nt][rr] + spb1[col]);
        }

    // ---- out = h + u @ pW2 + pb2, swapped operands: lane (m,q) owns
    //      node n0+m, chans nt*16+q*4..+3 -> vector load/store epilogue
    f32x4 acc3[4] = {z, z, z, z};
    #pragma unroll
    for (int ks = 0; ks < 2; ++ks) {
        const int k0 = ks * 32 + quad * 8;
        bf16x8 hfrag = *(const bf16x8*)&sHid[wave][m][k0];
        #pragma unroll
        for (int nt = 0; nt < 4; ++nt)
            acc3[nt] = mfma16(*(const bf16x8*)&sP2[nt * 16 + m][k0], hfrag, acc3[nt]);
    }
    {
        const int node = n0 + m;
        const float* hr = h + (size_t)node * DIM;
        float* orow = out + (size_t)node * DIM;
        #pragma unroll
        for (int nt = 0; nt < 4; ++nt) {
            const int c0 = nt * 16 + quad * 4;
            f32x4 hv = *(const f32x4*)(hr + c0);
            f32x4 bias = *(const f32x4*)&spb2[c0];
            f32x4 v;
            #pragma unroll
            for (int rr = 0; rr < 4; ++rr) v[rr] = acc3[nt][rr] + bias[rr] + hv[rr];
            __builtin_nontemporal_store(v, (f32x4*)(orow + c0));
        }
    }
}

extern "C" void kernel_launch(void* const* d_in, const int* in_sizes, int n_in,
                              void* d_out, int out_size, void* d_ws, size_t ws_size,
                              hipStream_t stream)
{
    const float* h   = (const float*)d_in[0];
    const int* ei    = (const int*)d_in[1];
    const float* eW1 = (const float*)d_in[2];
    const float* eb1 = (const float*)d_in[3];
    const float* eW2 = (const float*)d_in[4];
    const float* eb2 = (const float*)d_in[5];
    const float* qW1 = (const float*)d_in[6];
    const float* qb1 = (const float*)d_in[7];
    const float* qW2 = (const float*)d_in[8];
    const float* qb2 = (const float*)d_in[9];
    const float* pW1 = (const float*)d_in[10];
    const float* pb1 = (const float*)d_in[11];
    const float* pW2 = (const float*)d_in[12];
    const float* pb2 = (const float*)d_in[13];
    const float* al  = (const float*)d_in[14];
    const float* be  = (const float*)d_in[15];
    const float* ga  = (const float*)d_in[16];
    const float* de  = (const float*)d_in[17];
    const float* lam = (const float*)d_in[18];

    float* out = (float*)d_out;
    float* mij = out + (size_t)N_NODES * DIM;
    bf16_t* aggb = (bf16_t*)d_ws;                       // 6.4 MB bf16 agg
    bf16_t* hb   = aggb + (size_t)N_NODES * HID;        // 6.4 MB bf16 h copy
    float* qsc   = (float*)(hb + (size_t)N_NODES * DIM);// 0.8 MB qout scratch

    const int n8 = (N_NODES * DIM) / 8;                 // 400000

    init_kernel<<<(n8 + 255) / 256, 256, 0, stream>>>(h, hb, aggb, n8);
    edge_kernel<<<EDGE_GRID, 1024, 0, stream>>>(hb, ei, eW1, eb1, eW2, eb2, mij, aggb);
    node_q_kernel<<<NODE_GRID, 512, 0, stream>>>(h, aggb, qW1, qb1, qW2, qb2,
                                                 al, be, ga, de, lam, qsc);
    node_p_kernel<<<NODE_GRID, 512, 0, stream>>>(h, aggb, qsc, pW1, pb1, pW2, pb2, out);
}